// Round 5
// baseline (103.854 us; speedup 1.0000x reference)
//
#include <hip/hip_runtime.h>
#include <hip/hip_bf16.h>
#include <stdint.h>

// ---- types ----
typedef __attribute__((ext_vector_type(4))) int i32x4;   // 16 i8 MFMA frag / i32x4 accum

typedef const void __attribute__((address_space(1)))* gas_ptr;
typedef void __attribute__((address_space(3)))* las_ptr;
#define GLD16(g, l) __builtin_amdgcn_global_load_lds((gas_ptr)(g), (las_ptr)(l), 16, 0, 0)

// ---- problem sizes ----
#define NIMG 32
#define CIN  256
#define HWDIM 56
#define HPAD 58
#define OCH  256
#define SPATIAL (HWDIM*HWDIM)        // 3136
#define M_TOT (NIMG*SPATIAL)         // 100352
#define KTOT  2304                    // 9*256
#define NSTEP 36                      // K-steps of 64 i8

// workspace layout (bytes)
#define WT_OFF     27557888ull        // after xb: 32*58*58*256 i8
#define ALPHA_OFF  28147712ull        // after WT: 256*2304 i8

#define LDSBUF 24576                  // W(8KB) + A(16KB)

// =====================================================================
// Kernel 1: per-o alpha + ternary i8 weights transposed to WT[o][k], k = tap*256 + c
// =====================================================================
__global__ __launch_bounds__(256)
void prep_weights(const float* __restrict__ w1, const float* __restrict__ w2,
                  char* __restrict__ WT, float* __restrict__ alpha) {
    const int o = blockIdx.x;
    const int t = threadIdx.x;
    const float* p1 = w1 + o * KTOT;
    const float* p2 = w2 + o * KTOT;
    char* wo = WT + o * KTOT;

    float s1 = 0.f, s2 = 0.f;
    for (int i = t; i < KTOT; i += 256) {
        float a = p1[i], b = p2[i];
        s1 += fabsf(a);
        s2 += fabsf(b);
        int sg = ((a > 0.f) ? 1 : ((a < 0.f) ? -1 : 0))
               + ((b > 0.f) ? 1 : ((b < 0.f) ? -1 : 0));
        int c = i / 9;
        int tap = i - c * 9;
        wo[tap * 256 + c] = (char)sg;
    }
    __shared__ float red[8];
    #pragma unroll
    for (int off = 32; off > 0; off >>= 1) {
        s1 += __shfl_down(s1, off, 64);
        s2 += __shfl_down(s2, off, 64);
    }
    const int lane = t & 63, wv = t >> 6;
    if (lane == 0) { red[wv] = s1; red[4 + wv] = s2; }
    __syncthreads();
    if (t == 0) {
        float t1 = red[0] + red[1] + red[2] + red[3];
        float t2 = red[4] + red[5] + red[6] + red[7];
        alpha[o] = (t1 * (1.f / 2304.f) + t2 * (1.f / 2304.f)) * 0.5f;
    }
}

// =====================================================================
// Kernel 2: binarize + NCHW -> padded NHWC i8, including border zeroing.
// Grid = 32 * 58 blocks: one per (n, hp).
// =====================================================================
__global__ __launch_bounds__(256)
void binarize_kernel(const float* __restrict__ x, char* __restrict__ xb) {
    const int b  = blockIdx.x;
    const int n  = b / HPAD;
    const int hp = b % HPAD;
    const int t  = threadIdx.x;
    char* rowp = xb + ((size_t)n * HPAD + hp) * (HPAD * CIN);

    if (hp == 0 || hp == HPAD - 1) {
        int* ip = (int*)rowp;                 // 58*256 B = 3712 ints
        for (int i = t; i < 3712; i += 256) ip[i] = 0;
        return;
    }
    const int h = hp - 1;
    __shared__ __align__(4) char tile[HWDIM * 260];
    if (t < 224) {
        const int w  = t % HWDIM;
        const int cl = t / HWDIM;
        const float* xp = x + (size_t)n * (CIN * SPATIAL) + (size_t)h * HWDIM + w;
        for (int c0 = 0; c0 < CIN; c0 += 4) {
            int c = c0 + cl;
            float v = xp[(size_t)c * SPATIAL];
            tile[w * 260 + c] = (v > 0.f) ? 1 : ((v < 0.f) ? -1 : 0);
        }
    }
    // zero left/right pad columns of this row
    int* ip = (int*)rowp;
    if (t < 64) ip[t] = 0;                    // w = 0
    else if (t < 128) ip[3648 + (t - 64)] = 0;// w = 57
    __syncthreads();
    const int wv = t >> 6, lane = t & 63;
    char* op = rowp + CIN;                    // w starts at 1
    for (int w0 = 0; w0 < HWDIM; w0 += 4) {
        int w = w0 + wv;
        int val = *(const int*)&tile[w * 260 + lane * 4];
        *(int*)(op + (size_t)w * CIN + lane * 4) = val;
    }
}

// =====================================================================
// Kernel 3: i8 implicit-GEMM. Block = 128(o) x 256(sp), 4 waves of 128x64.
// Ring-3 LDS (72KB -> 2 blocks/CU). Intra-wave fragment pipeline:
//   STAGE(s+2) ; read wf47(s) ; MFMA half1 ;
//   [vmcnt(6)+barrier: stage s+1 visible] ; prefetch xf',wf03' from buf s+1 ;
//   MFMA half2 ; [lgkmcnt(0)+barrier: reads drained before buffer reuse]
// All LDS reads overlap MFMA clusters; no vmcnt(0) in steady state.
// =====================================================================
__global__ __launch_bounds__(256, 2)
void conv_kernel(const char* __restrict__ xb,
                 const char* __restrict__ WT,
                 const float* __restrict__ alpha,
                 float* __restrict__ out) {
    __shared__ __align__(16) char lds[3 * LDSBUF];

    const int t    = threadIdx.x;
    const int lane = t & 63;
    const int wv   = t >> 6;

    // XCD-aware bijective remap: 784 blocks = 8 XCDs * 98
    const int bid  = blockIdx.x;
    const int tid_ = (bid & 7) * 98 + (bid >> 3);
    const int nt   = tid_ & 1;        // o-tile (0/1)
    const int mt   = tid_ >> 1;       // sp-tile (0..391)
    const int o0   = nt * 128;
    const int m0   = mt * 256;

    // ---- staging sources (both-sides swizzle f(r) = (r>>1)&3 = (t>>3)&3) ----
    const int srow = t >> 2;
    const int scol = ((t & 3) ^ ((t >> 3) & 3)) * 16;
    const char* w_g0 = WT + (size_t)(o0 + srow) * KTOT + scol;
    const char* w_g1 = w_g0 + (size_t)64 * KTOT;
    const char* a_g[4];
    #pragma unroll
    for (int q = 0; q < 4; ++q) {
        int m  = m0 + srow + q * 64;
        int ni = m / SPATIAL;
        int sp = m - ni * SPATIAL;
        int h  = sp / HWDIM;
        int w  = sp - h * HWDIM;
        a_g[q] = xb + ((size_t)(ni * HPAD + h) * HPAD + w) * CIN + scol;
    }
    char* dstT = lds + t * 16;

    i32x4 acc[8][4];
    #pragma unroll
    for (int i = 0; i < 8; ++i)
        #pragma unroll
        for (int j = 0; j < 4; ++j)
            acc[i][j] = (i32x4){0, 0, 0, 0};

    // ---- read-side addressing ----
    const int rl    = lane & 15;
    const int slot  = ((lane >> 4) ^ ((rl >> 1) & 3)) * 16;  // swizzled 16B slot
    const int rdoff = rl * 64 + slot;
    const int aoffw = 8192 + wv * 4096;    // wave's 64-sp slice in A part

    #define STAGE(S, B)                                                     \
    {                                                                       \
        const int s_ = (S);                                                 \
        const int tap = s_ >> 2;                                            \
        const int kh = tap / 3, kw = tap - kh * 3;                          \
        const int aoff = (kh * HPAD + kw) * CIN + (s_ & 3) * 64;            \
        const int woff = s_ * 64;                                           \
        char* d = dstT + (B) * LDSBUF;                                      \
        GLD16(w_g0 + woff, d);                                              \
        GLD16(w_g1 + woff, d + 4096);                                       \
        GLD16(a_g[0] + aoff, d + 8192);                                     \
        GLD16(a_g[1] + aoff, d + 12288);                                    \
        GLD16(a_g[2] + aoff, d + 16384);                                    \
        GLD16(a_g[3] + aoff, d + 20480);                                    \
    }

    i32x4 wf[8];        // W fragments of current step (wf[0..3] prefetched)
    i32x4 xf[2][4];     // A fragments, double-buffered by step parity

    // prologue: stage 0,1; wait own stage-0 loads; barrier => stage 0 visible
    STAGE(0, 0);
    STAGE(1, 1);
    asm volatile("s_waitcnt vmcnt(6)\n\ts_barrier" ::: "memory");
    {
        const char* B0 = lds;
        #pragma unroll
        for (int j = 0; j < 4; ++j)
            xf[0][j] = *(const i32x4*)(B0 + aoffw + j * 1024 + rdoff);
        #pragma unroll
        for (int i = 0; i < 4; ++i)
            wf[i] = *(const i32x4*)(B0 + i * 1024 + rdoff);
    }

    #pragma unroll
    for (int s = 0; s < NSTEP; ++s) {
        const int cur = s % 3;
        const int nxt = (s + 1) % 3;
        const int p   = s & 1;
        const char* Wb = lds + cur * LDSBUF;

        if (s + 2 < NSTEP) STAGE(s + 2, (s + 2) % 3);

        #pragma unroll
        for (int i = 0; i < 4; ++i)
            wf[4 + i] = *(const i32x4*)(Wb + (4 + i) * 1024 + rdoff);

        __builtin_amdgcn_s_setprio(1);
        #pragma unroll
        for (int i = 0; i < 4; ++i)
            #pragma unroll
            for (int j = 0; j < 4; ++j)
                acc[i][j] = __builtin_amdgcn_mfma_i32_16x16x64_i8(
                    wf[i], xf[p][j], acc[i][j], 0, 0, 0);
        __builtin_amdgcn_s_setprio(0);

        // barrier M: all waves' stage s+1 loads retired => buf s+1 readable
        if (s < NSTEP - 2)
            asm volatile("s_waitcnt vmcnt(6)\n\ts_barrier" ::: "memory");
        else if (s == NSTEP - 2)
            asm volatile("s_waitcnt vmcnt(0)\n\ts_barrier" ::: "memory");

        if (s < NSTEP - 1) {
            const char* Nb = lds + nxt * LDSBUF;
            #pragma unroll
            for (int j = 0; j < 4; ++j)
                xf[p ^ 1][j] = *(const i32x4*)(Nb + aoffw + j * 1024 + rdoff);
            #pragma unroll
            for (int i = 0; i < 4; ++i)
                wf[i] = *(const i32x4*)(Nb + i * 1024 + rdoff);
        }

        __builtin_amdgcn_s_setprio(1);
        #pragma unroll
        for (int i = 4; i < 8; ++i)
            #pragma unroll
            for (int j = 0; j < 4; ++j)
                acc[i][j] = __builtin_amdgcn_mfma_i32_16x16x64_i8(
                    wf[i], xf[p][j], acc[i][j], 0, 0, 0);
        __builtin_amdgcn_s_setprio(0);

        // barrier E: all reads of old buffers drained before next overwrite
        if (s < NSTEP - 1)
            asm volatile("s_waitcnt lgkmcnt(0)\n\ts_barrier" ::: "memory");
    }

    // ---- epilogue: out[n][o][h][w] = acc * alpha[o] ----
    // D frag: col(sp) = lane&15, row(o) = (lane>>4)*4 + reg
    #pragma unroll
    for (int i = 0; i < 8; ++i) {
        const int ob = o0 + i * 16 + (lane >> 4) * 4;
        float al[4];
        #pragma unroll
        for (int r = 0; r < 4; ++r) al[r] = alpha[ob + r];
        #pragma unroll
        for (int j = 0; j < 4; ++j) {
            int m  = m0 + wv * 64 + j * 16 + rl;
            int ni = m / SPATIAL;
            int sp = m - ni * SPATIAL;
            long base = (long)ni * (OCH * SPATIAL) + sp;
            #pragma unroll
            for (int r = 0; r < 4; ++r) {
                out[base + (long)(ob + r) * SPATIAL] = (float)acc[i][j][r] * al[r];
            }
        }
    }
    #undef STAGE
}

// =====================================================================
extern "C" void kernel_launch(void* const* d_in, const int* in_sizes, int n_in,
                              void* d_out, int out_size, void* d_ws, size_t ws_size,
                              hipStream_t stream) {
    const float* x  = (const float*)d_in[0];
    const float* w1 = (const float*)d_in[1];
    const float* w2 = (const float*)d_in[2];
    float* out = (float*)d_out;

    char* ws = (char*)d_ws;
    char*  xb    = ws;
    char*  WT    = ws + WT_OFF;
    float* alpha = (float*)(ws + ALPHA_OFF);

    hipLaunchKernelGGL(prep_weights, dim3(OCH), dim3(256), 0, stream, w1, w2, WT, alpha);
    hipLaunchKernelGGL(binarize_kernel, dim3(NIMG * HPAD), dim3(256), 0, stream, x, xb);
    hipLaunchKernelGGL(conv_kernel, dim3(M_TOT / 128), dim3(256), 0, stream,
                       xb, WT, alpha, out);
}